// Round 6
// baseline (996.185 us; speedup 1.0000x reference)
//
#include <hip/hip_runtime.h>

#define N_NODES   100000
#define N_EDGES   1600000
#define N_FEAT    128
#define HIDDEN    64
#define NUM_GRAPHS 64
#define XPAD 130                              // LDS row stride: bank=(2r+k)%32 -> 2-way (free)
#define CHUNK   8192
#define NCHUNK  ((N_EDGES + CHUNK - 1) / CHUNK)   // 196
#define BSHIFT  8
#define NBUCKET ((N_NODES + 255) >> 8)            // 391 buckets of 256 nodes
#define OFFS_W  (NBUCKET + 1)                     // 392 entries per chunk

// ---------------------------------------------------------------------------
// K1: h = x @ W. lane = row (64 rows/block tile), wave w computes cols
// [16w,16w+16). x staged in LDS (pad 130); W read via wave-uniform scalar
// loads -> SGPR operand of v_fma.
// ---------------------------------------------------------------------------
__global__ __launch_bounds__(256) void gemm_xw(const float* __restrict__ x,
                                               const float* __restrict__ W,
                                               float* __restrict__ h) {
    __shared__ float xs[64 * XPAD];            // 33.3 KB
    const int tid  = threadIdx.x;
    const int lane = tid & 63;
    const int wid  = __builtin_amdgcn_readfirstlane(tid >> 6);  // force wave-uniform
    const int c0   = wid * 16;
    const int base = blockIdx.x * 64;

#pragma unroll
    for (int j = 0; j < 8; ++j) {
        const int flat = (tid + j * 256) * 4;
        const int r = flat >> 7, k = flat & 127;
        const int row = base + r;
        float4 v = make_float4(0.f, 0.f, 0.f, 0.f);
        if (row < N_NODES) v = *(const float4*)&x[(size_t)row * N_FEAT + k];
        xs[r * XPAD + k + 0] = v.x;
        xs[r * XPAD + k + 1] = v.y;
        xs[r * XPAD + k + 2] = v.z;
        xs[r * XPAD + k + 3] = v.w;
    }
    __syncthreads();

    float acc[16];
#pragma unroll
    for (int c = 0; c < 16; ++c) acc[c] = 0.f;

    const float* __restrict__ Wp = W + c0;     // wave-uniform pointer
#pragma unroll 4
    for (int k = 0; k < N_FEAT; ++k) {
        const float xv = xs[lane * XPAD + k];
#pragma unroll
        for (int c = 0; c < 16; ++c)
            acc[c] = fmaf(xv, Wp[k * HIDDEN + c], acc[c]);
    }

    const int row = base + lane;
    if (row < N_NODES) {
        float* hp = &h[(size_t)row * HIDDEN + c0];
#pragma unroll
        for (int c = 0; c < 16; c += 4)
            *(float4*)&hp[c] = make_float4(acc[c], acc[c + 1], acc[c + 2], acc[c + 3]);
    }
}

// ---------------------------------------------------------------------------
// K2: deg[dst] += 1 per edge (deg pre-zeroed; +1 self-loop applied in dis)
// ---------------------------------------------------------------------------
__global__ __launch_bounds__(256) void deg_kernel(const int* __restrict__ ei,
                                                  int* __restrict__ deg) {
    const int e = blockIdx.x * 256 + threadIdx.x;
    if (e < N_EDGES) atomicAdd(&deg[__builtin_nontemporal_load(&ei[N_EDGES + e])], 1);
}

// ---------------------------------------------------------------------------
// K3: dis[i] = rsqrt(deg[i] + 1)
// ---------------------------------------------------------------------------
__global__ __launch_bounds__(256) void dis_kernel(const int* __restrict__ deg,
                                                  float* __restrict__ dis) {
    const int i = blockIdx.x * 256 + threadIdx.x;
    if (i < N_NODES) dis[i] = rsqrtf((float)deg[i] + 1.0f);
}

// ---------------------------------------------------------------------------
// K4: partition edges into 391 dst-buckets (256 nodes each), per 8192-edge
// chunk, entirely in LDS; all global writes coalesced. offs[c][b] gives the
// absolute start of (chunk c, bucket b); offs[c][NBUCKET] = chunk end.
// The phase-1 LDS histogram atomicAdd return value is the in-bucket rank.
// ---------------------------------------------------------------------------
__global__ __launch_bounds__(512) void partition_kernel(const int* __restrict__ ei,
                                                        int* __restrict__ src_out,
                                                        int* __restrict__ dst_out,
                                                        int* __restrict__ offs) {
    __shared__ int hist[512];
    __shared__ int excl[512];
    __shared__ int ssrc[CHUNK];     // 32 KB
    __shared__ int sdst[CHUNK];     // 32 KB
    const int c = blockIdx.x;
    const int base = c * CHUNK;
    const int n = min(CHUNK, N_EDGES - base);
    const int t = threadIdx.x;
    hist[t] = 0;
    __syncthreads();

    int es[CHUNK / 512], ed[CHUNK / 512], rk[CHUNK / 512];
#pragma unroll
    for (int k = 0; k < CHUNK / 512; ++k) {
        const int i = t + k * 512;
        if (i < n) {
            ed[k] = __builtin_nontemporal_load(&ei[N_EDGES + base + i]);
            es[k] = __builtin_nontemporal_load(&ei[base + i]);
            rk[k] = atomicAdd(&hist[ed[k] >> BSHIFT], 1);
        }
    }
    __syncthreads();

    // exclusive scan over 512 buckets (Hillis-Steele, inclusive then subtract)
    const int cnt = hist[t];
    for (int off = 1; off < 512; off <<= 1) {
        const int v = (t >= off) ? hist[t - off] : 0;
        __syncthreads();
        hist[t] += v;
        __syncthreads();
    }
    excl[t] = hist[t] - cnt;
    __syncthreads();
    if (t <= NBUCKET) offs[c * OFFS_W + t] = base + excl[t];   // excl[NBUCKET] == n

    // scatter into LDS at bucket-sorted positions
#pragma unroll
    for (int k = 0; k < CHUNK / 512; ++k) {
        const int i = t + k * 512;
        if (i < n) {
            const int pos = excl[ed[k] >> BSHIFT] + rk[k];
            ssrc[pos] = es[k];
            sdst[pos] = ed[k];
        }
    }
    __syncthreads();

    // coalesced writeout
    for (int i = t; i < n; i += 512) {
        src_out[base + i] = ssrc[i];
        dst_out[base + i] = sdst[i];
    }
}

// ---------------------------------------------------------------------------
// K5: per-bucket aggregation with LDS accumulators (no global scatter at all).
// Block b owns nodes [b*256, b*256+256). Walks its segment in every chunk,
// gathers h[src] rows (wave = 64 features), ds_add_f32 into accum. Epilogue
// fuses self-loop + bias + relu + global_add_pool (batch sorted -> few
// atomic bursts per block). hn is never materialized.
// ---------------------------------------------------------------------------
__global__ __launch_bounds__(256) void agg_bucket(const int* __restrict__ offs,
                                                  const int* __restrict__ src_out,
                                                  const int* __restrict__ dst_out,
                                                  const float* __restrict__ h,
                                                  const float* __restrict__ dis,
                                                  const float* __restrict__ bias,
                                                  const int* __restrict__ batch,
                                                  float* __restrict__ u) {
    __shared__ float accum[256 * HIDDEN];   // 64 KB
    __shared__ float disl[256];
    const int b = blockIdx.x;
    const int lo = b << BSHIFT;
    const int nloc = min(256, N_NODES - lo);
    const int t = threadIdx.x;
    const int lane = t & 63;
    const int wv = t >> 6;

    const float4 z4 = make_float4(0.f, 0.f, 0.f, 0.f);
    for (int i = t * 4; i < 256 * HIDDEN; i += 1024) *(float4*)&accum[i] = z4;
    if (t < nloc) disl[t] = dis[lo + t];
    __syncthreads();

    for (int c = wv; c < NCHUNK; c += 4) {            // waves split chunks
        const int beg = offs[c * OFFS_W + b];
        const int end = offs[c * OFFS_W + b + 1];
        for (int j0 = beg; j0 < end; j0 += 64) {
            const int nn = min(64, end - j0);
            int sL = 0, dL = lo; float wL = 0.f;
            if (lane < nn) {
                sL = src_out[j0 + lane];
                dL = dst_out[j0 + lane];
                wL = dis[sL] * disl[dL - lo];
            }
            int i = 0;
            for (; i + 4 <= nn; i += 4) {
                const int s0 = __shfl(sL, i),     s1 = __shfl(sL, i + 1);
                const int s2 = __shfl(sL, i + 2), s3 = __shfl(sL, i + 3);
                const int d0 = __shfl(dL, i),     d1 = __shfl(dL, i + 1);
                const int d2 = __shfl(dL, i + 2), d3 = __shfl(dL, i + 3);
                const float w0 = __shfl(wL, i),     w1 = __shfl(wL, i + 1);
                const float w2 = __shfl(wL, i + 2), w3 = __shfl(wL, i + 3);
                const float v0 = h[(size_t)s0 * HIDDEN + lane];
                const float v1 = h[(size_t)s1 * HIDDEN + lane];
                const float v2 = h[(size_t)s2 * HIDDEN + lane];
                const float v3 = h[(size_t)s3 * HIDDEN + lane];
                atomicAdd(&accum[((d0 - lo) << 6) + lane], v0 * w0);
                atomicAdd(&accum[((d1 - lo) << 6) + lane], v1 * w1);
                atomicAdd(&accum[((d2 - lo) << 6) + lane], v2 * w2);
                atomicAdd(&accum[((d3 - lo) << 6) + lane], v3 * w3);
            }
            for (; i < nn; ++i) {
                const int si = __shfl(sL, i);
                const int di = __shfl(dL, i);
                const float wi = __shfl(wL, i);
                atomicAdd(&accum[((di - lo) << 6) + lane],
                          h[(size_t)si * HIDDEN + lane] * wi);
            }
        }
    }
    __syncthreads();

    // epilogue: self-loop + bias + relu, then pool (batch sorted)
    const float bc = bias[lane];
    float pacc = 0.f;
    int cur_g = -1;
    for (int nd = wv; nd < nloc; nd += 4) {
        const int node = lo + nd;
        const float dn = disl[nd];
        float v = accum[(nd << 6) + lane]
                + h[(size_t)node * HIDDEN + lane] * dn * dn + bc;
        v = fmaxf(v, 0.f);
        const int g = batch[node];
        if (g != cur_g) {
            if (cur_g >= 0) atomicAdd(&u[cur_g * HIDDEN + lane], pacc);
            pacc = 0.f;
            cur_g = g;
        }
        pacc += v;
    }
    if (cur_g >= 0) atomicAdd(&u[cur_g * HIDDEN + lane], pacc);
}

// ---------------------------------------------------------------------------
// K6: out[g] = relu(u[g] @ W1 + b1) @ W2 + b2
// ---------------------------------------------------------------------------
__global__ __launch_bounds__(64) void mlp_kernel(const float* __restrict__ u,
                                                 const float* __restrict__ W1,
                                                 const float* __restrict__ b1,
                                                 const float* __restrict__ W2,
                                                 const float* __restrict__ b2,
                                                 float* __restrict__ out) {
    __shared__ float W1s[HIDDEN * 16];
    __shared__ float W2s[16];
    __shared__ float b1s[16];
    const int t = threadIdx.x;
    for (int i = t; i < HIDDEN * 16; i += 64) W1s[i] = W1[i];
    if (t < 16) { W2s[t] = W2[t]; b1s[t] = b1[t]; }
    __syncthreads();
    if (t < NUM_GRAPHS) {
        float uu[HIDDEN];
#pragma unroll
        for (int k = 0; k < HIDDEN; ++k) uu[k] = u[t * HIDDEN + k];
        float o = b2[0];
#pragma unroll
        for (int j = 0; j < 16; ++j) {
            float s = b1s[j];
#pragma unroll
            for (int k = 0; k < HIDDEN; ++k) s = fmaf(uu[k], W1s[k * 16 + j], s);
            o = fmaf(fmaxf(s, 0.f), W2s[j], o);
        }
        out[t] = o;
    }
}

// ---------------------------------------------------------------------------
extern "C" void kernel_launch(void* const* d_in, const int* in_sizes, int n_in,
                              void* d_out, int out_size, void* d_ws, size_t ws_size,
                              hipStream_t stream) {
    const float* x  = (const float*)d_in[0];
    const float* W  = (const float*)d_in[1];
    const float* b  = (const float*)d_in[2];
    const float* W1 = (const float*)d_in[3];
    const float* b1 = (const float*)d_in[4];
    const float* W2 = (const float*)d_in[5];
    const float* b2 = (const float*)d_in[6];
    const int*   ei = (const int*)d_in[7];     // [2, E] flat: src = ei[e], dst = ei[E+e]
    const int* batch = (const int*)d_in[8];    // [N], sorted
    float* out = (float*)d_out;

    // workspace:
    //   h        N*64 f32         25.6 MB
    //   src_out  E int             6.4 MB
    //   dst_out  E int             6.4 MB
    //   offs     NCHUNK*392 int    0.3 MB
    //   deg      N int             0.4 MB
    //   dis      N f32             0.4 MB
    //   u        64*64 f32         16 KB
    float* h       = (float*)d_ws;
    int*   src_out = (int*)(h + (size_t)N_NODES * HIDDEN);
    int*   dst_out = src_out + N_EDGES;
    int*   offs    = dst_out + N_EDGES;
    int*   deg     = offs + NCHUNK * OFFS_W;
    float* dis     = (float*)(deg + N_NODES);
    float* u       = dis + N_NODES;

    hipMemsetAsync(deg, 0, N_NODES * sizeof(int), stream);
    hipMemsetAsync(u, 0, NUM_GRAPHS * HIDDEN * sizeof(float), stream);

    gemm_xw<<<(N_NODES + 63) / 64, 256, 0, stream>>>(x, W, h);
    deg_kernel<<<(N_EDGES + 255) / 256, 256, 0, stream>>>(ei, deg);
    dis_kernel<<<(N_NODES + 255) / 256, 256, 0, stream>>>(deg, dis);
    partition_kernel<<<NCHUNK, 512, 0, stream>>>(ei, src_out, dst_out, offs);
    agg_bucket<<<NBUCKET, 256, 0, stream>>>(offs, src_out, dst_out, h, dis, b, batch, u);
    mlp_kernel<<<1, 64, 0, stream>>>(u, W1, b1, W2, b2, out);
}

// Round 7
// 261.817 us; speedup vs baseline: 3.8049x; 3.8049x over previous
//
#include <hip/hip_runtime.h>

#define N_NODES   100000
#define N_EDGES   1600000
#define N_FEAT    128
#define HIDDEN    64
#define NUM_GRAPHS 64
#define XPAD 130                              // LDS row stride: bank=(2r+k)%32 -> 2-way (free)
#define CHUNK   8192
#define NCHUNK  ((N_EDGES + CHUNK - 1) / CHUNK)   // 196
#define BSHIFT  8
#define NBUCKET ((N_NODES + 255) >> 8)            // 391 buckets of 256 nodes
#define OFFS_W  (NBUCKET + 1)                     // 392 entries per chunk

// ---------------------------------------------------------------------------
// K1: h = x @ W. lane = row, wave w computes cols [16w,16w+16). x in LDS,
// W via wave-uniform scalar loads (SGPR operand of v_fma).
// ---------------------------------------------------------------------------
__global__ __launch_bounds__(256) void gemm_xw(const float* __restrict__ x,
                                               const float* __restrict__ W,
                                               float* __restrict__ h) {
    __shared__ float xs[64 * XPAD];            // 33.3 KB
    const int tid  = threadIdx.x;
    const int lane = tid & 63;
    const int wid  = __builtin_amdgcn_readfirstlane(tid >> 6);
    const int c0   = wid * 16;
    const int base = blockIdx.x * 64;

#pragma unroll
    for (int j = 0; j < 8; ++j) {
        const int flat = (tid + j * 256) * 4;
        const int r = flat >> 7, k = flat & 127;
        const int row = base + r;
        float4 v = make_float4(0.f, 0.f, 0.f, 0.f);
        if (row < N_NODES) v = *(const float4*)&x[(size_t)row * N_FEAT + k];
        xs[r * XPAD + k + 0] = v.x;
        xs[r * XPAD + k + 1] = v.y;
        xs[r * XPAD + k + 2] = v.z;
        xs[r * XPAD + k + 3] = v.w;
    }
    __syncthreads();

    float acc[16];
#pragma unroll
    for (int c = 0; c < 16; ++c) acc[c] = 0.f;

    const float* __restrict__ Wp = W + c0;
#pragma unroll 4
    for (int k = 0; k < N_FEAT; ++k) {
        const float xv = xs[lane * XPAD + k];
#pragma unroll
        for (int c = 0; c < 16; ++c)
            acc[c] = fmaf(xv, Wp[k * HIDDEN + c], acc[c]);
    }

    const int row = base + lane;
    if (row < N_NODES) {
        float* hp = &h[(size_t)row * HIDDEN + c0];
#pragma unroll
        for (int c = 0; c < 16; c += 4)
            *(float4*)&hp[c] = make_float4(acc[c], acc[c + 1], acc[c + 2], acc[c + 3]);
    }
}

// ---------------------------------------------------------------------------
// K2: partition edges into 391 dst-buckets per 8192-edge chunk, via LDS; all
// global writes coalesced. offs[c][b] = absolute start of (chunk c, bucket b).
// Also accumulates total bucket sizes (bucket_size pre-zeroed).
// ---------------------------------------------------------------------------
__global__ __launch_bounds__(512) void partition_kernel(const int* __restrict__ ei,
                                                        int* __restrict__ src_out,
                                                        int* __restrict__ dst_out,
                                                        int* __restrict__ offs,
                                                        int* __restrict__ bucket_size) {
    __shared__ int hist[512];
    __shared__ int excl[512];
    __shared__ int ssrc[CHUNK];     // 32 KB
    __shared__ int sdst[CHUNK];     // 32 KB
    const int c = blockIdx.x;
    const int base = c * CHUNK;
    const int n = min(CHUNK, N_EDGES - base);
    const int t = threadIdx.x;
    hist[t] = 0;
    __syncthreads();

    int es[CHUNK / 512], ed[CHUNK / 512], rk[CHUNK / 512];
#pragma unroll
    for (int k = 0; k < CHUNK / 512; ++k) {
        const int i = t + k * 512;
        if (i < n) {
            ed[k] = __builtin_nontemporal_load(&ei[N_EDGES + base + i]);
            es[k] = __builtin_nontemporal_load(&ei[base + i]);
            rk[k] = atomicAdd(&hist[ed[k] >> BSHIFT], 1);
        }
    }
    __syncthreads();

    const int cnt = hist[t];
    for (int off = 1; off < 512; off <<= 1) {
        const int v = (t >= off) ? hist[t - off] : 0;
        __syncthreads();
        hist[t] += v;
        __syncthreads();
    }
    excl[t] = hist[t] - cnt;
    __syncthreads();
    if (t <= NBUCKET) offs[c * OFFS_W + t] = base + excl[t];   // excl[NBUCKET]==n
    if (t < NBUCKET && cnt > 0) atomicAdd(&bucket_size[t], cnt);

#pragma unroll
    for (int k = 0; k < CHUNK / 512; ++k) {
        const int i = t + k * 512;
        if (i < n) {
            const int pos = excl[ed[k] >> BSHIFT] + rk[k];
            ssrc[pos] = es[k];
            sdst[pos] = ed[k];
        }
    }
    __syncthreads();

    for (int i = t; i < n; i += 512) {
        src_out[base + i] = ssrc[i];
        dst_out[base + i] = sdst[i];
    }
}

// ---------------------------------------------------------------------------
// K3: exclusive scan of bucket_size -> bucket_start (1 block).
// ---------------------------------------------------------------------------
__global__ __launch_bounds__(512) void scan_buckets(const int* __restrict__ bucket_size,
                                                    int* __restrict__ bucket_start) {
    __shared__ int s[512];
    const int t = threadIdx.x;
    const int v = (t < NBUCKET) ? bucket_size[t] : 0;
    s[t] = v;
    __syncthreads();
    for (int off = 1; off < 512; off <<= 1) {
        const int a = (t >= off) ? s[t - off] : 0;
        __syncthreads();
        s[t] += a;
        __syncthreads();
    }
    if (t < NBUCKET) bucket_start[t] = s[t] - v;
}

// ---------------------------------------------------------------------------
// K4: per-bucket CSR finalize. Block b owns nodes [b*256, b*256+256) and the
// private output window srcs[bucket_start[b] .. +size). Two streaming passes
// over the bucket's chunk segments (waves parallel over chunks):
//  pass1: node histogram (LDS) -> scan -> row_ptr/row_end/dis (coalesced)
//  pass2: scatter src into the block-private window (stores combine in the
//         owning CU's L2 -> ~full-line writebacks, unlike the R4/R5 global
//         scatter where 8 XCDs interleaved writes to shared windows).
// ---------------------------------------------------------------------------
__global__ __launch_bounds__(512) void bucket_csr(const int* __restrict__ offs,
                                                  const int* __restrict__ src_tmp,
                                                  const int* __restrict__ dst_tmp,
                                                  const int* __restrict__ bucket_start,
                                                  int* __restrict__ srcs,
                                                  int* __restrict__ row_ptr,
                                                  int* __restrict__ row_end,
                                                  float* __restrict__ dis) {
    __shared__ int hist[256];
    __shared__ int nxt[256];
    __shared__ int segb[NCHUNK], sege[NCHUNK];
    const int b = blockIdx.x;
    const int lo = b << BSHIFT;
    const int t = threadIdx.x;
    const int lane = t & 63;
    const int wv = t >> 6;                      // 8 waves
    const int bstart = bucket_start[b];

    if (t < 256) hist[t] = 0;
    for (int c = t; c < NCHUNK; c += 512) {
        segb[c] = offs[c * OFFS_W + b];
        sege[c] = offs[c * OFFS_W + b + 1];
    }
    __syncthreads();

    for (int c = wv; c < NCHUNK; c += 8)
        for (int i = segb[c] + lane; i < sege[c]; i += 64)
            atomicAdd(&hist[dst_tmp[i] - lo], 1);
    __syncthreads();

    const int cnt = (t < 256) ? hist[t] : 0;
    for (int off = 1; off < 256; off <<= 1) {
        int v = 0;
        if (t < 256 && t >= off) v = hist[t - off];
        __syncthreads();
        if (t < 256) hist[t] += v;
        __syncthreads();
    }
    if (t < 256) {
        const int excl = hist[t] - cnt;
        nxt[t] = excl;
        const int node = lo + t;
        if (node < N_NODES) {
            row_ptr[node] = bstart + excl;
            row_end[node] = bstart + excl + cnt;
            dis[node]     = rsqrtf((float)cnt + 1.0f);
        }
    }
    __syncthreads();

    for (int c = wv; c < NCHUNK; c += 8)
        for (int i = segb[c] + lane; i < sege[c]; i += 64) {
            const int d = dst_tmp[i] - lo;
            const int s = src_tmp[i];
            const int pos = atomicAdd(&nxt[d], 1);
            srcs[bstart + pos] = s;
        }
}

// ---------------------------------------------------------------------------
// K5: per-node gather-aggregate (R4 version). One wave per node; lane L:
// edge subgroup L>>4, columns (L&15)*4..+3 as float4.
// ---------------------------------------------------------------------------
__global__ __launch_bounds__(256) void agg_kernel(const int* __restrict__ row_ptr,
                                                  const int* __restrict__ row_end,
                                                  const int* __restrict__ srcs,
                                                  const float* __restrict__ h,
                                                  const float* __restrict__ dis,
                                                  const float* __restrict__ bias,
                                                  float* __restrict__ hn) {
    const int node = blockIdx.x * 4 + (threadIdx.x >> 6);
    if (node >= N_NODES) return;
    const int lane = threadIdx.x & 63;
    const int q    = lane >> 4;
    const int c4   = (lane & 15) * 4;
    const int beg = row_ptr[node];
    const int end = row_end[node];
    const float dn = dis[node];
    float4 acc = make_float4(0.f, 0.f, 0.f, 0.f);

    for (int j0 = beg; j0 < end; j0 += 64) {
        const int n = min(64, end - j0);
        int s = 0; float w = 0.f;
        if (lane < n) { s = srcs[j0 + lane]; w = dis[s] * dn; }
        const int ng = (n + 3) >> 2;
        for (int i = 0; i < ng; ++i) {
            const int idx = i * 4 + q;
            const int   si = __shfl(s, idx);
            const float wi = __shfl(w, idx);
            const float4 v = *(const float4*)&h[(size_t)si * HIDDEN + c4];
            acc.x = fmaf(v.x, wi, acc.x);
            acc.y = fmaf(v.y, wi, acc.y);
            acc.z = fmaf(v.z, wi, acc.z);
            acc.w = fmaf(v.w, wi, acc.w);
        }
    }
    acc.x += __shfl_xor(acc.x, 16); acc.y += __shfl_xor(acc.y, 16);
    acc.z += __shfl_xor(acc.z, 16); acc.w += __shfl_xor(acc.w, 16);
    acc.x += __shfl_xor(acc.x, 32); acc.y += __shfl_xor(acc.y, 32);
    acc.z += __shfl_xor(acc.z, 32); acc.w += __shfl_xor(acc.w, 32);

    if (lane < 16) {
        const float4 hv = *(const float4*)&h[(size_t)node * HIDDEN + c4];
        const float4 bv = *(const float4*)&bias[c4];
        const float d2 = dn * dn;
        float4 r;
        r.x = fmaxf(fmaf(hv.x, d2, acc.x) + bv.x, 0.f);
        r.y = fmaxf(fmaf(hv.y, d2, acc.y) + bv.y, 0.f);
        r.z = fmaxf(fmaf(hv.z, d2, acc.z) + bv.z, 0.f);
        r.w = fmaxf(fmaf(hv.w, d2, acc.w) + bv.w, 0.f);
        *(float4*)&hn[(size_t)node * HIDDEN + c4] = r;
    }
}

// ---------------------------------------------------------------------------
// K6: global_add_pool — wave per 16-node slice, local accumulate, one atomic
// burst per graph switch (batch sorted). u pre-zeroed.
// ---------------------------------------------------------------------------
__global__ __launch_bounds__(256) void pool_kernel(const float* __restrict__ hn,
                                                   const int* __restrict__ batch,
                                                   float* __restrict__ u) {
    const int chunk = blockIdx.x * 64;
    const int lane = threadIdx.x & 63;
    const int wv = threadIdx.x >> 6;
    const int lim = min(chunk + 64, N_NODES);
    float acc = 0.f;
    int cur_g = -1;
    for (int node = chunk + wv; node < lim; node += 4) {
        const int g = batch[node];
        if (g != cur_g) {
            if (cur_g >= 0) atomicAdd(&u[cur_g * HIDDEN + lane], acc);
            acc = 0.f;
            cur_g = g;
        }
        acc += hn[(size_t)node * HIDDEN + lane];
    }
    if (cur_g >= 0) atomicAdd(&u[cur_g * HIDDEN + lane], acc);
}

// ---------------------------------------------------------------------------
// K7: out[g] = relu(u[g] @ W1 + b1) @ W2 + b2
// ---------------------------------------------------------------------------
__global__ __launch_bounds__(64) void mlp_kernel(const float* __restrict__ u,
                                                 const float* __restrict__ W1,
                                                 const float* __restrict__ b1,
                                                 const float* __restrict__ W2,
                                                 const float* __restrict__ b2,
                                                 float* __restrict__ out) {
    __shared__ float W1s[HIDDEN * 16];
    __shared__ float W2s[16];
    __shared__ float b1s[16];
    const int t = threadIdx.x;
    for (int i = t; i < HIDDEN * 16; i += 64) W1s[i] = W1[i];
    if (t < 16) { W2s[t] = W2[t]; b1s[t] = b1[t]; }
    __syncthreads();
    if (t < NUM_GRAPHS) {
        float uu[HIDDEN];
#pragma unroll
        for (int k = 0; k < HIDDEN; ++k) uu[k] = u[t * HIDDEN + k];
        float o = b2[0];
#pragma unroll
        for (int j = 0; j < 16; ++j) {
            float s = b1s[j];
#pragma unroll
            for (int k = 0; k < HIDDEN; ++k) s = fmaf(uu[k], W1s[k * 16 + j], s);
            o = fmaf(fmaxf(s, 0.f), W2s[j], o);
        }
        out[t] = o;
    }
}

// ---------------------------------------------------------------------------
extern "C" void kernel_launch(void* const* d_in, const int* in_sizes, int n_in,
                              void* d_out, int out_size, void* d_ws, size_t ws_size,
                              hipStream_t stream) {
    const float* x  = (const float*)d_in[0];
    const float* W  = (const float*)d_in[1];
    const float* b  = (const float*)d_in[2];
    const float* W1 = (const float*)d_in[3];
    const float* b1 = (const float*)d_in[4];
    const float* W2 = (const float*)d_in[5];
    const float* b2 = (const float*)d_in[6];
    const int*   ei = (const int*)d_in[7];     // [2, E] flat
    const int* batch = (const int*)d_in[8];    // [N], sorted
    float* out = (float*)d_out;

    // workspace (~59 MB):
    //   h        : N*64 f32                      25.6 MB
    //   hn       : N*64 f32 — ALIASES src_tmp/dst_tmp region (dead by agg)
    //   src_tmp  : E int  (= hn base)             6.4 MB
    //   dst_tmp  : E int                          6.4 MB
    //   (hn tail)                                12.8 MB
    //   srcs     : E int                          6.4 MB
    //   offs/row_ptr/row_end/dis/buckets/u        ~1.6 MB
    float* h        = (float*)d_ws;
    float* hn       = h + (size_t)N_NODES * HIDDEN;
    int*   src_tmp  = (int*)hn;
    int*   dst_tmp  = src_tmp + N_EDGES;
    int*   srcs     = (int*)(hn + (size_t)N_NODES * HIDDEN);
    int*   offs     = srcs + N_EDGES;
    int*   row_ptr  = offs + NCHUNK * OFFS_W;
    int*   row_end  = row_ptr + N_NODES;
    float* dis      = (float*)(row_end + N_NODES);
    int*   bucket_size  = (int*)(dis + N_NODES);
    int*   bucket_start = bucket_size + 512;
    float* u        = (float*)(bucket_start + 512);

    hipMemsetAsync(bucket_size, 0, 512 * sizeof(int), stream);
    hipMemsetAsync(u, 0, NUM_GRAPHS * HIDDEN * sizeof(float), stream);

    gemm_xw<<<(N_NODES + 63) / 64, 256, 0, stream>>>(x, W, h);
    partition_kernel<<<NCHUNK, 512, 0, stream>>>(ei, src_tmp, dst_tmp, offs, bucket_size);
    scan_buckets<<<1, 512, 0, stream>>>(bucket_size, bucket_start);
    bucket_csr<<<NBUCKET, 512, 0, stream>>>(offs, src_tmp, dst_tmp, bucket_start,
                                            srcs, row_ptr, row_end, dis);
    agg_kernel<<<(N_NODES + 3) / 4, 256, 0, stream>>>(row_ptr, row_end, srcs, h, dis, b, hn);
    pool_kernel<<<(N_NODES + 63) / 64, 256, 0, stream>>>(hn, batch, u);
    mlp_kernel<<<1, 64, 0, stream>>>(u, W1, b1, W2, b2, out);
}